// Round 3
// baseline (2084.407 us; speedup 1.0000x reference)
//
#include <hip/hip_runtime.h>

#define N_NODES 50000
#define N_EDGES 500000
#define EMB 50
#define HID 64
#define OUTD 50
#define EDIM 28
#define HEADS 4
#define F1 256              // HEADS*HID
#define NEG 0.2f
#define EPS_SM 1e-16f
#define EPS_LN 1e-5f

typedef unsigned short u16;
typedef unsigned int u32;

__device__ __forceinline__ float b2f(u16 u) { return __uint_as_float(((u32)u) << 16); }
__device__ __forceinline__ u16 f2b(float f) {
    u32 u = __float_as_uint(f);
    u32 r = (u + 0x7FFFu + ((u >> 16) & 1u)) >> 16;
    return (u16)r;
}
__device__ __forceinline__ float lrelu(float x) { return x > 0.f ? x : NEG * x; }

__device__ __forceinline__ void atomicMaxF(float* a, float v) {
    int* ai = (int*)a;
    int old = __float_as_int(*a);
    while (__int_as_float(old) < v) {
        int assumed = old;
        old = atomicCAS(ai, assumed, __float_as_int(v));
        if (old == assumed) break;
    }
}

__global__ void k_fill(float* p, float v, int n) {
    int i = blockIdx.x * blockDim.x + threadIdx.x;
    if (i < n) p[i] = v;
}

// ---- conv1 node transform: xl = h0 @ Wl1 + bl1, xr = h0 @ Wr1 + br1, h0 = emb[x[n]]
// weights bf16-compressed into LDS (fp32 pair would be 205KB > 160KB); outputs bf16
__global__ __launch_bounds__(256) void k_node1(
    const int* __restrict__ x, const float* __restrict__ emb,
    const float* __restrict__ Wl, const float* __restrict__ bl,
    const float* __restrict__ Wr, const float* __restrict__ br,
    u16* __restrict__ xl, u16* __restrict__ xr)
{
    __shared__ u16 wls[EMB * F1];
    __shared__ u16 wrs[EMB * F1];
    __shared__ float bls[F1], brs[F1], h0s[EMB];
    int tid = threadIdx.x;
    for (int i = tid; i < EMB * F1; i += 256) { wls[i] = f2b(Wl[i]); wrs[i] = f2b(Wr[i]); }
    bls[tid] = bl[tid]; brs[tid] = br[tid];
    __syncthreads();
    for (int n = blockIdx.x; n < N_NODES; n += gridDim.x) {
        if (tid < EMB) h0s[tid] = emb[(size_t)x[n] * EMB + tid];
        __syncthreads();
        float al = bls[tid], ar = brs[tid];
        #pragma unroll 5
        for (int k = 0; k < EMB; k++) {
            float h = h0s[k];
            al += h * b2f(wls[k * F1 + tid]);
            ar += h * b2f(wrs[k * F1 + tid]);
        }
        xl[(size_t)n * F1 + tid] = f2b(al);
        xr[(size_t)n * F1 + tid] = f2b(ar);
        __syncthreads();
    }
}

// ---- conv1 edge: xe = ea @ We1, m = lrelu(xl[s]+xr[d]+xe), logits = <m,att>, segment max
// We1/att1 staged in LDS (fp32, 29.7KB); 32 edges per block (wave handles one edge at a time)
__global__ __launch_bounds__(256) void k_edge1(
    const int* __restrict__ srcA, const int* __restrict__ dstA,
    const float* __restrict__ ea, const u16* __restrict__ xl, const u16* __restrict__ xr,
    const float* __restrict__ We, const float* __restrict__ att,
    float* __restrict__ logits, float* __restrict__ amax)
{
    __shared__ float wes[EDIM * F1];
    __shared__ float atts[F1];
    int tid = threadIdx.x;
    for (int i = tid; i < EDIM * F1; i += 256) wes[i] = We[i];
    if (tid < F1) atts[tid] = att[tid];
    __syncthreads();
    int lane = tid & 63;
    int sub = tid >> 6;
    int base = blockIdx.x * 32;
    for (int it = 0; it < 8; it++) {
        int e = base + it * 4 + sub;
        if (e >= N_EDGES) continue;
        int s = srcA[e], d = dstA[e];
        const float* ep = ea + (size_t)e * EDIM;
        float x0 = 0, x1 = 0, x2 = 0, x3 = 0;
        #pragma unroll 7
        for (int k = 0; k < EDIM; k++) {
            float ev = ep[k];                      // broadcast load (same addr across wave)
            const float* w = wes + k * F1 + lane;  // bank = lane%32: 2-way, free
            x0 += ev * w[0];
            x1 += ev * w[64];
            x2 += ev * w[128];
            x3 += ev * w[192];
        }
        const u16* xls = xl + (size_t)s * F1 + lane;
        const u16* xrd = xr + (size_t)d * F1 + lane;
        float p0 = lrelu(b2f(xls[0])   + b2f(xrd[0])   + x0) * atts[lane];
        float p1 = lrelu(b2f(xls[64])  + b2f(xrd[64])  + x1) * atts[64 + lane];
        float p2 = lrelu(b2f(xls[128]) + b2f(xrd[128]) + x2) * atts[128 + lane];
        float p3 = lrelu(b2f(xls[192]) + b2f(xrd[192]) + x3) * atts[192 + lane];
        #pragma unroll
        for (int off = 32; off > 0; off >>= 1) {
            p0 += __shfl_xor(p0, off);
            p1 += __shfl_xor(p1, off);
            p2 += __shfl_xor(p2, off);
            p3 += __shfl_xor(p3, off);
        }
        if (lane == 0) {
            float* lp = logits + (size_t)e * 4;
            lp[0] = p0; lp[1] = p1; lp[2] = p2; lp[3] = p3;
            atomicMaxF(amax + (size_t)d * 4 + 0, p0);
            atomicMaxF(amax + (size_t)d * 4 + 1, p1);
            atomicMaxF(amax + (size_t)d * 4 + 2, p2);
            atomicMaxF(amax + (size_t)d * 4 + 3, p3);
        }
    }
}

__global__ void k_softmax1(const int* __restrict__ dstA, float* __restrict__ logits,
                           const float* __restrict__ amax, float* __restrict__ denom)
{
    int i = blockIdx.x * blockDim.x + threadIdx.x;
    if (i >= N_EDGES * 4) return;
    int e = i >> 2, h = i & 3;
    int d = dstA[e];
    float ex = expf(logits[i] - amax[d * 4 + h]);
    logits[i] = ex;
    atomicAdd(denom + d * 4 + h, ex);
}

__global__ __launch_bounds__(256) void k_agg1(
    const int* __restrict__ srcA, const int* __restrict__ dstA,
    const float* __restrict__ alpha, const float* __restrict__ denom,
    const u16* __restrict__ xl, float* __restrict__ out)
{
    int gid = blockIdx.x * blockDim.x + threadIdx.x;
    int e = gid >> 6;
    if (e >= N_EDGES) return;
    int lane = threadIdx.x & 63;
    int s = srcA[e], d = dstA[e];
    float a0 = alpha[(size_t)e * 4 + 0] / (denom[d * 4 + 0] + EPS_SM);
    float a1 = alpha[(size_t)e * 4 + 1] / (denom[d * 4 + 1] + EPS_SM);
    float a2 = alpha[(size_t)e * 4 + 2] / (denom[d * 4 + 2] + EPS_SM);
    float a3 = alpha[(size_t)e * 4 + 3] / (denom[d * 4 + 3] + EPS_SM);
    const u16* xs = xl + (size_t)s * F1 + lane;
    float* od = out + (size_t)d * F1 + lane;
    atomicAdd(od + 0,   a0 * b2f(xs[0]));
    atomicAdd(od + 64,  a1 * b2f(xs[64]));
    atomicAdd(od + 128, a2 * b2f(xs[128]));
    atomicAdd(od + 192, a3 * b2f(xs[192]));
}

// ---- graph LayerNorm pass 1: accumulate S1, S2 over whole tensor (out-bias folded in)
__global__ __launch_bounds__(256) void k_ln_reduce(
    const float* __restrict__ v, const float* __restrict__ bias,
    int M, int C, float* __restrict__ S)
{
    float s = 0, s2 = 0;
    int stride = gridDim.x * blockDim.x;
    for (int i = blockIdx.x * blockDim.x + threadIdx.x; i < M; i += stride) {
        float xv = v[i] + bias[i % C];
        s += xv; s2 += xv * xv;
    }
    #pragma unroll
    for (int off = 32; off > 0; off >>= 1) { s += __shfl_xor(s, off); s2 += __shfl_xor(s2, off); }
    __shared__ float ws[4], ws2[4];
    int wid = threadIdx.x >> 6;
    if ((threadIdx.x & 63) == 0) { ws[wid] = s; ws2[wid] = s2; }
    __syncthreads();
    if (threadIdx.x == 0) {
        float a = 0, b = 0;
        for (int w = 0; w < 4; w++) { a += ws[w]; b += ws2[w]; }
        atomicAdd(S, a); atomicAdd(S + 1, b);
    }
}

// in-place LN apply + ReLU
__global__ void k_ln_apply_relu(
    float* v, const float* __restrict__ bias,
    const float* __restrict__ w, const float* __restrict__ b,
    const float* __restrict__ S, int M, int C)
{
    int i = blockIdx.x * blockDim.x + threadIdx.x;
    if (i >= M) return;
    float mu = S[0] / (float)M;
    float var = S[1] / (float)M - mu * mu;
    float inv = 1.f / (sqrtf(fmaxf(var, 0.f)) + EPS_LN);
    int c = i % C;
    float xv = v[i] + bias[c];
    float y = (xv - mu) * inv * w[c] + b[c];
    v[i] = fmaxf(y, 0.f);
}

__global__ void k_ln_out(
    const float* __restrict__ v, const float* __restrict__ bias,
    const float* __restrict__ w, const float* __restrict__ b,
    const float* __restrict__ S, int M, int C, float* __restrict__ out)
{
    int i = blockIdx.x * blockDim.x + threadIdx.x;
    if (i >= M) return;
    float mu = S[0] / (float)M;
    float var = S[1] / (float)M - mu * mu;
    float inv = 1.f / (sqrtf(fmaxf(var, 0.f)) + EPS_LN);
    int c = i % C;
    float xv = v[i] + bias[c];
    out[i] = (xv - mu) * inv * w[c] + b[c];
}

// ---- conv2 node transform (heads=1, C=50)
__global__ __launch_bounds__(128) void k_node2(
    const float* __restrict__ h, const float* __restrict__ Wl, const float* __restrict__ bl,
    const float* __restrict__ Wr, const float* __restrict__ br,
    float* __restrict__ xl, float* __restrict__ xr)
{
    __shared__ u16 wls[F1 * OUTD];
    __shared__ u16 wrs[F1 * OUTD];
    __shared__ float hs[F1];
    int tid = threadIdx.x;
    for (int i = tid; i < F1 * OUTD; i += 128) { wls[i] = f2b(Wl[i]); wrs[i] = f2b(Wr[i]); }
    __syncthreads();
    for (int n = blockIdx.x; n < N_NODES; n += gridDim.x) {
        hs[tid] = h[(size_t)n * F1 + tid];
        hs[tid + 128] = h[(size_t)n * F1 + tid + 128];
        __syncthreads();
        bool isL = (tid < OUTD);
        bool isR = (tid >= 64 && tid < 64 + OUTD);
        if (isL || isR) {
            int col = isL ? tid : tid - 64;
            const u16* W = isL ? wls : wrs;
            float acc = isL ? bl[col] : br[col];
            #pragma unroll 8
            for (int k = 0; k < F1; k++) acc += hs[k] * b2f(W[k * OUTD + col]);
            (isL ? xl : xr)[(size_t)n * OUTD + col] = acc;
        }
        __syncthreads();
    }
}

__global__ __launch_bounds__(256) void k_edge2(
    const int* __restrict__ srcA, const int* __restrict__ dstA,
    const float* __restrict__ ea, const float* __restrict__ xl, const float* __restrict__ xr,
    const float* __restrict__ We, const float* __restrict__ att,
    float* __restrict__ logits, float* __restrict__ amax)
{
    __shared__ float wes[EDIM * OUTD];
    __shared__ float atts[OUTD];
    int tid = threadIdx.x;
    for (int i = tid; i < EDIM * OUTD; i += 256) wes[i] = We[i];
    if (tid < OUTD) atts[tid] = att[tid];
    __syncthreads();
    int lane = tid & 63;
    int sub = tid >> 6;
    int base = blockIdx.x * 32;
    for (int it = 0; it < 8; it++) {
        int e = base + it * 4 + sub;
        if (e >= N_EDGES) continue;
        int s = srcA[e], d = dstA[e];
        float p = 0.f;
        if (lane < OUTD) {
            const float* ep = ea + (size_t)e * EDIM;
            float acc = 0.f;
            #pragma unroll 7
            for (int k = 0; k < EDIM; k++) acc += ep[k] * wes[k * OUTD + lane];
            float m = lrelu(xl[(size_t)s * OUTD + lane] + xr[(size_t)d * OUTD + lane] + acc);
            p = m * atts[lane];
        }
        #pragma unroll
        for (int off = 32; off > 0; off >>= 1) p += __shfl_xor(p, off);
        if (lane == 0) {
            logits[e] = p;
            atomicMaxF(amax + d, p);
        }
    }
}

__global__ void k_softmax2(const int* __restrict__ dstA, float* __restrict__ logits,
                           const float* __restrict__ amax, float* __restrict__ denom)
{
    int e = blockIdx.x * blockDim.x + threadIdx.x;
    if (e >= N_EDGES) return;
    int d = dstA[e];
    float ex = expf(logits[e] - amax[d]);
    logits[e] = ex;
    atomicAdd(denom + d, ex);
}

__global__ __launch_bounds__(256) void k_agg2(
    const int* __restrict__ srcA, const int* __restrict__ dstA,
    const float* __restrict__ alpha, const float* __restrict__ denom,
    const float* __restrict__ xl, float* __restrict__ out)
{
    int gid = blockIdx.x * blockDim.x + threadIdx.x;
    int e = gid >> 6;
    if (e >= N_EDGES) return;
    int lane = threadIdx.x & 63;
    int s = srcA[e], d = dstA[e];
    float a = alpha[e] / (denom[d] + EPS_SM);
    if (lane < OUTD)
        atomicAdd(out + (size_t)d * OUTD + lane, a * xl[(size_t)s * OUTD + lane]);
}

extern "C" void kernel_launch(void* const* d_in, const int* in_sizes, int n_in,
                              void* d_out, int out_size, void* d_ws, size_t ws_size,
                              hipStream_t stream)
{
    const int*   x    = (const int*)d_in[0];
    const int*   ei   = (const int*)d_in[1];
    const int*   srcA = ei;
    const int*   dstA = ei + N_EDGES;
    const float* ea   = (const float*)d_in[2];
    const float* emb  = (const float*)d_in[3];
    const float* Wl1  = (const float*)d_in[4];
    const float* bl1  = (const float*)d_in[5];
    const float* Wr1  = (const float*)d_in[6];
    const float* br1  = (const float*)d_in[7];
    const float* We1  = (const float*)d_in[8];
    const float* att1 = (const float*)d_in[9];
    const float* bias1= (const float*)d_in[10];
    const float* ln1w = (const float*)d_in[11];
    const float* ln1b = (const float*)d_in[12];
    const float* Wl2  = (const float*)d_in[13];
    const float* bl2  = (const float*)d_in[14];
    const float* Wr2  = (const float*)d_in[15];
    const float* br2  = (const float*)d_in[16];
    const float* We2  = (const float*)d_in[17];
    const float* att2 = (const float*)d_in[18];
    const float* bias2= (const float*)d_in[19];
    const float* ln2w = (const float*)d_in[20];
    const float* ln2b = (const float*)d_in[21];

    // workspace layout (float offsets), peak 22,300,004 floats = 89.2 MB
    // liveness-based overlap:
    //   out1 [6.4M,19.2M) overlaps xr1b [6.4M,12.8M)  (xr1b dead after edge1; memset after edge1)
    //   xl2/xr2 [0,5M) overlap xl1b                   (dead after agg1)
    //   alpha2 [19.2M,19.7M) reuses alpha1            (dead after agg1)
    //   out2 [19.7M,22.2M) overlaps alpha1 tail + amax1/denom1 (dead after agg1)
    float* W = (float*)d_ws;
    u16*   xl1b   = (u16*)W;                     // N*F1 u16 -> floats [0, 6.4M)
    u16*   xr1b   = (u16*)(W + 6400000);         // N*F1 u16 -> floats [6.4M, 12.8M)
    float* out1   = W + 6400000;                 // N*F1 f32  [6.4M, 19.2M)
    float* alpha1 = W + 19200000;                // E*4       [19.2M, 21.2M)
    float* amax1  = W + 21200000;                // 200k
    float* denom1 = W + 21400000;                // 200k
    float* xl2    = W;                           // 2.5M
    float* xr2    = W + 2500000;                 // 2.5M
    float* alpha2 = W + 19200000;                // 0.5M
    float* out2   = W + 19700000;                // 2.5M      [19.7M, 22.2M)
    float* amax2  = W + 22200000;                // 50k
    float* denom2 = W + 22250000;                // 50k
    float* S      = W + 22300000;                // 4
    float* h1     = out1;                        // LN1 applied in place

    hipMemsetAsync(denom1, 0, N_NODES * 4 * sizeof(float), stream);
    hipMemsetAsync(denom2, 0, N_NODES * sizeof(float), stream);
    hipMemsetAsync(S, 0, 4 * sizeof(float), stream);
    k_fill<<<(N_NODES * 4 + 255) / 256, 256, 0, stream>>>(amax1, -1e30f, N_NODES * 4);
    k_fill<<<(N_NODES + 255) / 256, 256, 0, stream>>>(amax2, -1e30f, N_NODES);

    // conv1
    k_node1<<<800, 256, 0, stream>>>(x, emb, Wl1, bl1, Wr1, br1, xl1b, xr1b);
    k_edge1<<<N_EDGES / 32, 256, 0, stream>>>(srcA, dstA, ea, xl1b, xr1b, We1, att1, alpha1, amax1);
    hipMemsetAsync(out1, 0, (size_t)N_NODES * F1 * sizeof(float), stream);  // xr1b dead now
    k_softmax1<<<(N_EDGES * 4 + 255) / 256, 256, 0, stream>>>(dstA, alpha1, amax1, denom1);
    k_agg1<<<(N_EDGES * 64) / 256, 256, 0, stream>>>(srcA, dstA, alpha1, denom1, xl1b, out1);
    k_ln_reduce<<<2048, 256, 0, stream>>>(out1, bias1, N_NODES * F1, F1, S);
    k_ln_apply_relu<<<(N_NODES * F1 + 255) / 256, 256, 0, stream>>>(out1, bias1, ln1w, ln1b, S, N_NODES * F1, F1);

    // conv2
    k_node2<<<1600, 128, 0, stream>>>(h1, Wl2, bl2, Wr2, br2, xl2, xr2);
    hipMemsetAsync(out2, 0, (size_t)N_NODES * OUTD * sizeof(float), stream); // alpha1/amax1/denom1 dead
    k_edge2<<<N_EDGES / 32, 256, 0, stream>>>(srcA, dstA, ea, xl2, xr2, We2, att2, alpha2, amax2);
    k_softmax2<<<(N_EDGES + 255) / 256, 256, 0, stream>>>(dstA, alpha2, amax2, denom2);
    k_agg2<<<(N_EDGES * 64) / 256, 256, 0, stream>>>(srcA, dstA, alpha2, denom2, xl2, out2);
    k_ln_reduce<<<1024, 256, 0, stream>>>(out2, bias2, N_NODES * OUTD, OUTD, S + 2);
    k_ln_out<<<(N_NODES * OUTD + 255) / 256, 256, 0, stream>>>(out2, bias2, ln2w, ln2b, S + 2, N_NODES * OUTD, OUTD, (float*)d_out);
}